// Round 7
// baseline (114.095 us; speedup 1.0000x reference)
//
#include <hip/hip_runtime.h>
#include <hip/hip_bf16.h>

typedef __bf16 bf16x8 __attribute__((ext_vector_type(8)));
typedef float f32x4 __attribute__((ext_vector_type(4)));
typedef float f32x16 __attribute__((ext_vector_type(16)));
typedef unsigned int u32x2 __attribute__((ext_vector_type(2)));
typedef unsigned int u32x4 __attribute__((ext_vector_type(4)));

#define MFMA16(a, b, c) __builtin_amdgcn_mfma_f32_16x16x32_bf16((a), (b), (c), 0, 0, 0)
#define MFMA32(a, b, c) __builtin_amdgcn_mfma_f32_32x32x16_bf16((a), (b), (c), 0, 0, 0)

// ---- constants ----
#define BATCH 8
#define SEQ 512
#define HID 768
#define NHEAD 12
#define HDIM 64

__device__ __forceinline__ unsigned short f2bf(float f) {
    unsigned int u = __float_as_uint(f);
    u += 0x7fffu + ((u >> 16) & 1u);
    return (unsigned short)(u >> 16);
}

__device__ __forceinline__ unsigned int cvtpk_bf16(float lo, float hi) {
    unsigned int r;
    asm("v_cvt_pk_bf16_f32 %0, %1, %2" : "=v"(r) : "v"(lo), "v"(hi));
    return r;
}

// ---- fused fp32 -> bf16 convert (hidden_states + 3 weights, one dispatch) ----
__global__ __launch_bounds__(256) void cvt_all_kernel(const float4* __restrict__ hs,
                                                      const float4* __restrict__ Wq,
                                                      const float4* __restrict__ Wk,
                                                      const float4* __restrict__ Wv,
                                                      ushort4* __restrict__ hsb,
                                                      ushort4* __restrict__ wb) {
    int i = blockIdx.x * 256 + threadIdx.x;
    float4 v;
    ushort4* dst;
    if (i < 786432) {
        v = hs[i];
        dst = hsb + i;
    } else {
        int j = i - 786432;
        int which = j / 147456;
        int jj = j - which * 147456;
        const float4* src = (which == 0) ? Wq : ((which == 1) ? Wk : Wv);
        v = src[jj];
        dst = wb + j;
    }
    ushort4 o;
    o.x = f2bf(v.x); o.y = f2bf(v.y); o.z = f2bf(v.z); o.w = f2bf(v.w);
    *dst = o;
}

// ---- fused QKV GEMM v3: barrier-free direct-global, 32x32x16 MFMA ----
// C[m,n] = sum_k hs[m,k] * W[n,k].  Block = 4 waves (2x2); wave owns 64x64 out
// via 2x2 f32x16 accs. A/B fragments read straight from global (L2-resident
// per XCD remap); no LDS, no __syncthreads -> no vmcnt(0) barrier drains.
__global__ __launch_bounds__(256) void qkv_gemm_kernel(const unsigned short* __restrict__ hsb,
                                                       const unsigned short* __restrict__ wb,
                                                       const float* __restrict__ bq,
                                                       const float* __restrict__ bk,
                                                       const float* __restrict__ bv,
                                                       unsigned short* __restrict__ Qb,
                                                       unsigned short* __restrict__ Kb,
                                                       unsigned short* __restrict__ VTb) {
    const int tid = threadIdx.x;
    const int w = tid >> 6;
    const int l = tid & 63;
    const int lq = l & 31, h5 = l >> 5;
    const int wr = w >> 1, wc = w & 1;

    // XCD-aware remap: xcd = id&7 owns an 8Mx9N tile rectangle (3.4MB working set < 4MB L2)
    const int id = blockIdx.x;            // 0..575
    const int xcd = id & 7, j = id >> 3;  // j in [0,72) = 8 x 9
    const int tm = (xcd >> 1) * 8 + j / 9;   // 0..31
    const int tn = (xcd & 1) * 9 + j % 9;    // 0..17
    const int m0 = tm * 128;
    const int n0 = tn * 128;

    // fragment base pointers: lane lq = row, h5 picks k-half of each K=16 step
    const unsigned short* pA = hsb + (size_t)(m0 + wr * 64 + lq) * HID + h5 * 8;
    const unsigned short* pB = wb  + (size_t)(n0 + wc * 64 + lq) * HID + h5 * 8;

    f32x16 acc00 = {}, acc01 = {}, acc10 = {}, acc11 = {};

#pragma unroll 4
    for (int kt = 0; kt < 48; ++kt) {
        bf16x8 a0 = *reinterpret_cast<const bf16x8*>(pA + kt * 16);
        bf16x8 a1 = *reinterpret_cast<const bf16x8*>(pA + 32 * HID + kt * 16);
        bf16x8 b0 = *reinterpret_cast<const bf16x8*>(pB + kt * 16);
        bf16x8 b1 = *reinterpret_cast<const bf16x8*>(pB + 32 * HID + kt * 16);
        acc00 = MFMA32(a0, b0, acc00);
        acc01 = MFMA32(a0, b1, acc01);
        acc10 = MFMA32(a1, b0, acc10);
        acc11 = MFMA32(a1, b1, acc11);
    }

    // epilogue: bias add, Q pre-scale 1/8, scatter to head layouts.
    // C/D: col = lq, row = (r&3) + 8*(r>>2) + 4*h5  (r in [0,16))
    f32x16 accs[2][2] = {{acc00, acc01}, {acc10, acc11}};
#pragma unroll
    for (int ni = 0; ni < 2; ++ni) {
        int col = n0 + wc * 64 + ni * 32 + lq;    // 0..2303
        int which = col / HID;                    // 0=Q 1=K 2=V
        int oo = col - which * HID;
        int head = oo >> 6, d = oo & 63;
        const float* bias = (which == 0) ? bq : ((which == 1) ? bk : bv);
        float bvv = bias[oo];
#pragma unroll
        for (int mi = 0; mi < 2; ++mi) {
            f32x16 a = accs[mi][ni];
#pragma unroll
            for (int g = 0; g < 4; ++g) {
                int row0 = m0 + wr * 64 + mi * 32 + 8 * g + 4 * h5;   // 4-aligned
                int bi = row0 >> 9;
                int s0 = row0 & 511;
                if (which == 2) {
                    ushort4 pk;
                    pk.x = f2bf(a[4 * g + 0] + bvv);
                    pk.y = f2bf(a[4 * g + 1] + bvv);
                    pk.z = f2bf(a[4 * g + 2] + bvv);
                    pk.w = f2bf(a[4 * g + 3] + bvv);
                    *reinterpret_cast<ushort4*>(
                        &VTb[((size_t)(bi * NHEAD + head) * HDIM + d) * SEQ + s0]) = pk;
                } else {
                    unsigned short* dst = (which == 0) ? Qb : Kb;
                    float scale = (which == 0) ? 0.125f : 1.0f;
#pragma unroll
                    for (int r2 = 0; r2 < 4; ++r2) {
                        dst[((size_t)(bi * NHEAD + head) * SEQ + (s0 + r2)) * HDIM + d] =
                            f2bf((a[4 * g + r2] + bvv) * scale);
                    }
                }
            }
        }
    }
}

// ---- attention v4b (unchanged): swapped-QK^T 32x32 MFMA, in-register softmax ----
__global__ __launch_bounds__(256, 3) void attn_kernel(const unsigned short* __restrict__ Qb,
                                                      const unsigned short* __restrict__ Kb,
                                                      const unsigned short* __restrict__ VTb,
                                                      const float* __restrict__ mask,
                                                      float* __restrict__ out) {
    __shared__ float lds_ctx[2][32][64];   // 16 KB
    __shared__ float lds_den[2][32];       // 256 B

    const int tid = threadIdx.x;
    const int w = tid >> 6;
    const int l = tid & 63;
    const int lq = l & 31;
    const int h5 = l >> 5;
    const int qg = w & 1;
    const int kh = w >> 1;

    const int id = blockIdx.x;   // 0..767
    const int hh = id % 96;      // same XCD for all qb of a head (96 % 8 == 0)
    const int qb = id / 96;
    const int b = hh / 12;
    const int hd = hh % 12;

    const size_t headoff = ((size_t)b * NHEAD + hd) * SEQ * HDIM;
    const size_t vtoff   = headoff;
    const int q0 = qb * 64 + qg * 32;
    const float4* mask4 = (const float4*)mask;

    bf16x8 qf[4];
#pragma unroll
    for (int dc = 0; dc < 4; ++dc)
        qf[dc] = *reinterpret_cast<const bf16x8*>(
            &Qb[headoff + (size_t)(q0 + lq) * HDIM + dc * 16 + h5 * 8]);

    f32x16 ctx0 = {};
    f32x16 ctx1 = {};
    float den = 0.f;

#pragma unroll 1
    for (int kb = 0; kb < 8; ++kb) {
        const int k0 = kh * 256 + kb * 32;

        bf16x8 kf[4];
#pragma unroll
        for (int dc = 0; dc < 4; ++dc)
            kf[dc] = *reinterpret_cast<const bf16x8*>(
                &Kb[headoff + (size_t)(k0 + lq) * HDIM + dc * 16 + h5 * 8]);

        f32x16 T = {};
#pragma unroll
        for (int dc = 0; dc < 4; ++dc)
            T = MFMA32(kf[dc], qf[dc], T);

        bf16x8 vf00 = *reinterpret_cast<const bf16x8*>(&VTb[vtoff + (size_t)(lq) * SEQ + k0 + h5 * 8]);
        bf16x8 vf10 = *reinterpret_cast<const bf16x8*>(&VTb[vtoff + (size_t)(lq) * SEQ + k0 + 16 + h5 * 8]);
        bf16x8 vf01 = *reinterpret_cast<const bf16x8*>(&VTb[vtoff + (size_t)(32 + lq) * SEQ + k0 + h5 * 8]);
        bf16x8 vf11 = *reinterpret_cast<const bf16x8*>(&VTb[vtoff + (size_t)(32 + lq) * SEQ + k0 + 16 + h5 * 8]);

        float4 mv[4];
#pragma unroll
        for (int g = 0; g < 4; ++g)
            mv[g] = mask4[b * 128 + (k0 >> 2) + 2 * g + h5];

        float p[16];
#pragma unroll
        for (int r = 0; r < 16; ++r) {
            float mval = (r & 3) == 0 ? mv[r >> 2].x : ((r & 3) == 1 ? mv[r >> 2].y
                       : ((r & 3) == 2 ? mv[r >> 2].z : mv[r >> 2].w));
            p[r] = __expf(T[r] + mval);
            den += p[r];
        }

        bf16x8 pa[2];
#pragma unroll
        for (int c = 0; c < 2; ++c) {
            int base = c * 8;
            unsigned int lo01 = cvtpk_bf16(p[base + 0], p[base + 1]);
            unsigned int lo23 = cvtpk_bf16(p[base + 2], p[base + 3]);
            unsigned int hi01 = cvtpk_bf16(p[base + 4], p[base + 5]);
            unsigned int hi23 = cvtpk_bf16(p[base + 6], p[base + 7]);
            u32x2 s1 = __builtin_amdgcn_permlane32_swap(lo01, hi01, false, false);  // {w0, w2}
            u32x2 s2 = __builtin_amdgcn_permlane32_swap(lo23, hi23, false, false);  // {w1, w3}
            u32x4 words = {s1[0], s2[0], s1[1], s2[1]};
            pa[c] = __builtin_bit_cast(bf16x8, words);
        }

        ctx0 = MFMA32(pa[0], vf00, ctx0);
        ctx0 = MFMA32(pa[1], vf10, ctx0);
        ctx1 = MFMA32(pa[0], vf01, ctx1);
        ctx1 = MFMA32(pa[1], vf11, ctx1);
    }

    float den_full = den + __shfl_xor(den, 32);

    if (kh == 1) {
        if (l < 32) lds_den[qg][l] = den_full;
#pragma unroll
        for (int r = 0; r < 16; ++r) {
            int qr = (r & 3) + 8 * (r >> 2) + 4 * h5;
            lds_ctx[qg][qr][lq] = ctx0[r];
            lds_ctx[qg][qr][32 + lq] = ctx1[r];
        }
    }
    __syncthreads();
    if (kh == 0) {
        float den_tot = den_full + lds_den[qg][lq];
#pragma unroll
        for (int r = 0; r < 16; ++r) {
            int qr = (r & 3) + 8 * (r >> 2) + 4 * h5;
            float dn = 1.0f / __shfl(den_tot, qr);
            size_t rowoff = ((size_t)b * SEQ + q0 + qr) * HID + hd * HDIM;
            out[rowoff + lq]      = (ctx0[r] + lds_ctx[qg][qr][lq]) * dn;
            out[rowoff + 32 + lq] = (ctx1[r] + lds_ctx[qg][qr][32 + lq]) * dn;
        }
    }
}

extern "C" void kernel_launch(void* const* d_in, const int* in_sizes, int n_in,
                              void* d_out, int out_size, void* d_ws, size_t ws_size,
                              hipStream_t stream) {
    const float* hs   = (const float*)d_in[0];
    const float* mask = (const float*)d_in[1];
    const float* Wq   = (const float*)d_in[2];
    const float* bq   = (const float*)d_in[3];
    const float* Wk   = (const float*)d_in[4];
    const float* bk   = (const float*)d_in[5];
    const float* Wv   = (const float*)d_in[6];
    const float* bv   = (const float*)d_in[7];
    float* out = (float*)d_out;

    char* ws = (char*)d_ws;
    unsigned short* hsb = (unsigned short*)(ws);
    unsigned short* wb  = (unsigned short*)(ws + 6291456);
    unsigned short* Qb  = (unsigned short*)(ws + 9830400);
    unsigned short* Kb  = (unsigned short*)(ws + 16121856);
    unsigned short* VTb = (unsigned short*)(ws + 22413312);

    cvt_all_kernel<<<4800, 256, 0, stream>>>((const float4*)hs, (const float4*)Wq,
                                             (const float4*)Wk, (const float4*)Wv,
                                             (ushort4*)hsb, (ushort4*)wb);
    qkv_gemm_kernel<<<576, 256, 0, stream>>>(hsb, wb, bq, bk, bv, Qb, Kb, VTb);
    attn_kernel<<<768, 256, 0, stream>>>(Qb, Kb, VTb, mask, out);
}

// Round 8
// 78.971 us; speedup vs baseline: 1.4448x; 1.4448x over previous
//
#include <hip/hip_runtime.h>
#include <hip/hip_bf16.h>

typedef __bf16 bf16x8 __attribute__((ext_vector_type(8)));
typedef float f32x4 __attribute__((ext_vector_type(4)));
typedef float f32x16 __attribute__((ext_vector_type(16)));
typedef unsigned int u32x2 __attribute__((ext_vector_type(2)));
typedef unsigned int u32x4 __attribute__((ext_vector_type(4)));

#define MFMA16(a, b, c) __builtin_amdgcn_mfma_f32_16x16x32_bf16((a), (b), (c), 0, 0, 0)
#define MFMA32(a, b, c) __builtin_amdgcn_mfma_f32_32x32x16_bf16((a), (b), (c), 0, 0, 0)

// ---- constants ----
#define BATCH 8
#define SEQ 512
#define HID 768
#define NHEAD 12
#define HDIM 64

typedef const unsigned int __attribute__((address_space(1))) *gptr_t;
typedef unsigned int __attribute__((address_space(3))) *lptr_t;

__device__ __forceinline__ unsigned short f2bf(float f) {
    unsigned int u = __float_as_uint(f);
    u += 0x7fffu + ((u >> 16) & 1u);
    return (unsigned short)(u >> 16);
}

__device__ __forceinline__ unsigned int cvtpk_bf16(float lo, float hi) {
    unsigned int r;
    asm("v_cvt_pk_bf16_f32 %0, %1, %2" : "=v"(r) : "v"(lo), "v"(hi));
    return r;
}

// ---- fused fp32 -> bf16 convert (hidden_states + 3 weights, one dispatch) ----
__global__ __launch_bounds__(256) void cvt_all_kernel(const float4* __restrict__ hs,
                                                      const float4* __restrict__ Wq,
                                                      const float4* __restrict__ Wk,
                                                      const float4* __restrict__ Wv,
                                                      ushort4* __restrict__ hsb,
                                                      ushort4* __restrict__ wb) {
    int i = blockIdx.x * 256 + threadIdx.x;
    float4 v;
    ushort4* dst;
    if (i < 786432) {
        v = hs[i];
        dst = hsb + i;
    } else {
        int j = i - 786432;
        int which = j / 147456;
        int jj = j - which * 147456;
        const float4* src = (which == 0) ? Wq : ((which == 1) ? Wk : Wv);
        v = src[jj];
        dst = wb + j;
    }
    ushort4 o;
    o.x = f2bf(v.x); o.y = f2bf(v.y); o.z = f2bf(v.z); o.w = f2bf(v.w);
    *dst = o;
}

// ---- fused QKV GEMM v4: LDS-staged (R6 pattern) + counted-vmcnt pipeline ----
// Tri-buffered BK=32 tiles, 2-deep prefetch. Per iter: vmcnt(4) [counted, NOT 0]
// -> raw s_barrier -> stage(kt+2) -> ds_read+MFMA. Loads span the barrier and
// land during the next two compute phases (T3+T4).
__global__ __launch_bounds__(256) void qkv_gemm_kernel(const unsigned short* __restrict__ hsb,
                                                       const unsigned short* __restrict__ wb,
                                                       const float* __restrict__ bq,
                                                       const float* __restrict__ bk,
                                                       const float* __restrict__ bv,
                                                       unsigned short* __restrict__ Qb,
                                                       unsigned short* __restrict__ Kb,
                                                       unsigned short* __restrict__ VTb) {
    __shared__ __align__(16) unsigned short lsA[3][128 * 32];   // 24 KB
    __shared__ __align__(16) unsigned short lsB[3][128 * 32];   // 24 KB

    const int tid = threadIdx.x;
    const int w = tid >> 6;
    const int l = tid & 63;
    const int r16 = l & 15, g4 = l >> 4;
    const int wr = w >> 1, wc = w & 1;

    // XCD-aware remap: xcd = id&7 owns an 8Mx9N tile rectangle (3.4MB < 4MB L2)
    const int id = blockIdx.x;            // 0..575
    const int xcd = id & 7, j = id >> 3;  // j in [0,72) = 8 x 9
    const int tm = (xcd >> 1) * 8 + j / 9;   // 0..31
    const int tn = (xcd & 1) * 9 + j % 9;    // 0..17
    const int m0 = tm * 128;
    const int n0 = tn * 128;

    f32x4 acc[4][4];
#pragma unroll
    for (int i = 0; i < 4; ++i)
#pragma unroll
        for (int jj = 0; jj < 4; ++jj)
            acc[i][jj] = (f32x4){0.f, 0.f, 0.f, 0.f};

    // stage K-tile kt into buffer buf (4 global_load_lds per thread = vmcnt 4/wave).
    // LDS dest linear; global source chunk-XOR'd (rule 21: inverse-swz source).
    auto stage = [&](int kt, int buf) {
        const int k0 = kt * 32;
#pragma unroll
        for (int r = 0; r < 2; ++r) {
            int c = r * 256 + tid;               // 0..511
            int row = c >> 2;
            int cc = (c & 3) ^ (row & 3);
            const unsigned short* ga = hsb + (size_t)(m0 + row) * HID + k0 + cc * 8;
            __builtin_amdgcn_global_load_lds((gptr_t)(const void*)ga,
                (lptr_t)(void*)(&lsA[buf][(size_t)(r * 256 + w * 64) * 8]), 16, 0, 0);
            const unsigned short* gb = wb + (size_t)(n0 + row) * HID + k0 + cc * 8;
            __builtin_amdgcn_global_load_lds((gptr_t)(const void*)gb,
                (lptr_t)(void*)(&lsB[buf][(size_t)(r * 256 + w * 64) * 8]), 16, 0, 0);
        }
    };

    auto compute = [&](int cur) {
        bf16x8 af[4], bfr[4];
#pragma unroll
        for (int mi = 0; mi < 4; ++mi) {
            int row = wr * 64 + mi * 16 + r16;
            af[mi] = *reinterpret_cast<const bf16x8*>(
                &lsA[cur][row * 32 + ((g4 ^ (row & 3)) * 8)]);
        }
#pragma unroll
        for (int ni = 0; ni < 4; ++ni) {
            int row = wc * 64 + ni * 16 + r16;
            bfr[ni] = *reinterpret_cast<const bf16x8*>(
                &lsB[cur][row * 32 + ((g4 ^ (row & 3)) * 8)]);
        }
#pragma unroll
        for (int mi = 0; mi < 4; ++mi)
#pragma unroll
            for (int ni = 0; ni < 4; ++ni)
                acc[mi][ni] = MFMA16(af[mi], bfr[ni], acc[mi][ni]);
    };

    stage(0, 0);
    stage(1, 1);

#pragma unroll 1
    for (int kt = 0; kt < 24; ++kt) {
        // wait for stage(kt) only; stage(kt+1) stays in flight across the barrier
        if (kt < 23) {
            asm volatile("s_waitcnt vmcnt(4)" ::: "memory");
        } else {
            asm volatile("s_waitcnt vmcnt(0)" ::: "memory");
        }
        __builtin_amdgcn_s_barrier();
        asm volatile("" ::: "memory");
        // safe: all waves' ds_reads of buf (kt+2)%3 (== buf of iter kt-1) finished
        // before they could arrive at the barrier above.
        if (kt + 2 < 24) stage(kt + 2, (kt + 2) % 3);
        compute(kt % 3);
    }

    // epilogue: bias add, Q pre-scale by 1/8, scatter to head layouts
#pragma unroll
    for (int ni = 0; ni < 4; ++ni) {
        int col = n0 + wc * 64 + ni * 16 + r16;
        int which = col / HID;
        int oo = col - which * HID;
        int head = oo >> 6, d = oo & 63;
        const float* bias = (which == 0) ? bq : ((which == 1) ? bk : bv);
        float bvv = bias[oo];
#pragma unroll
        for (int mi = 0; mi < 4; ++mi) {
            int row0 = m0 + wr * 64 + mi * 16 + g4 * 4;
            int bi = row0 >> 9;
            int s0 = row0 & 511;
            if (which == 2) {
                ushort4 pk;
                pk.x = f2bf(acc[mi][ni][0] + bvv);
                pk.y = f2bf(acc[mi][ni][1] + bvv);
                pk.z = f2bf(acc[mi][ni][2] + bvv);
                pk.w = f2bf(acc[mi][ni][3] + bvv);
                *reinterpret_cast<ushort4*>(
                    &VTb[((size_t)(bi * NHEAD + head) * HDIM + d) * SEQ + s0]) = pk;
            } else {
                unsigned short* dst = (which == 0) ? Qb : Kb;
                float scale = (which == 0) ? 0.125f : 1.0f;
#pragma unroll
                for (int r = 0; r < 4; ++r) {
                    dst[((size_t)(bi * NHEAD + head) * SEQ + (s0 + r)) * HDIM + d] =
                        f2bf((acc[mi][ni][r] + bvv) * scale);
                }
            }
        }
    }
}

// ---- attention v4b (unchanged): swapped-QK^T 32x32 MFMA, in-register softmax ----
__global__ __launch_bounds__(256, 3) void attn_kernel(const unsigned short* __restrict__ Qb,
                                                      const unsigned short* __restrict__ Kb,
                                                      const unsigned short* __restrict__ VTb,
                                                      const float* __restrict__ mask,
                                                      float* __restrict__ out) {
    __shared__ float lds_ctx[2][32][64];   // 16 KB
    __shared__ float lds_den[2][32];       // 256 B

    const int tid = threadIdx.x;
    const int w = tid >> 6;
    const int l = tid & 63;
    const int lq = l & 31;
    const int h5 = l >> 5;
    const int qg = w & 1;
    const int kh = w >> 1;

    const int id = blockIdx.x;   // 0..767
    const int hh = id % 96;      // same XCD for all qb of a head (96 % 8 == 0)
    const int qb = id / 96;
    const int b = hh / 12;
    const int hd = hh % 12;

    const size_t headoff = ((size_t)b * NHEAD + hd) * SEQ * HDIM;
    const size_t vtoff   = headoff;
    const int q0 = qb * 64 + qg * 32;
    const float4* mask4 = (const float4*)mask;

    bf16x8 qf[4];
#pragma unroll
    for (int dc = 0; dc < 4; ++dc)
        qf[dc] = *reinterpret_cast<const bf16x8*>(
            &Qb[headoff + (size_t)(q0 + lq) * HDIM + dc * 16 + h5 * 8]);

    f32x16 ctx0 = {};
    f32x16 ctx1 = {};
    float den = 0.f;

#pragma unroll 1
    for (int kb = 0; kb < 8; ++kb) {
        const int k0 = kh * 256 + kb * 32;

        bf16x8 kf[4];
#pragma unroll
        for (int dc = 0; dc < 4; ++dc)
            kf[dc] = *reinterpret_cast<const bf16x8*>(
                &Kb[headoff + (size_t)(k0 + lq) * HDIM + dc * 16 + h5 * 8]);

        f32x16 T = {};
#pragma unroll
        for (int dc = 0; dc < 4; ++dc)
            T = MFMA32(kf[dc], qf[dc], T);

        bf16x8 vf00 = *reinterpret_cast<const bf16x8*>(&VTb[vtoff + (size_t)(lq) * SEQ + k0 + h5 * 8]);
        bf16x8 vf10 = *reinterpret_cast<const bf16x8*>(&VTb[vtoff + (size_t)(lq) * SEQ + k0 + 16 + h5 * 8]);
        bf16x8 vf01 = *reinterpret_cast<const bf16x8*>(&VTb[vtoff + (size_t)(32 + lq) * SEQ + k0 + h5 * 8]);
        bf16x8 vf11 = *reinterpret_cast<const bf16x8*>(&VTb[vtoff + (size_t)(32 + lq) * SEQ + k0 + 16 + h5 * 8]);

        float4 mv[4];
#pragma unroll
        for (int g = 0; g < 4; ++g)
            mv[g] = mask4[b * 128 + (k0 >> 2) + 2 * g + h5];

        float p[16];
#pragma unroll
        for (int r = 0; r < 16; ++r) {
            float mval = (r & 3) == 0 ? mv[r >> 2].x : ((r & 3) == 1 ? mv[r >> 2].y
                       : ((r & 3) == 2 ? mv[r >> 2].z : mv[r >> 2].w));
            p[r] = __expf(T[r] + mval);
            den += p[r];
        }

        bf16x8 pa[2];
#pragma unroll
        for (int c = 0; c < 2; ++c) {
            int base = c * 8;
            unsigned int lo01 = cvtpk_bf16(p[base + 0], p[base + 1]);
            unsigned int lo23 = cvtpk_bf16(p[base + 2], p[base + 3]);
            unsigned int hi01 = cvtpk_bf16(p[base + 4], p[base + 5]);
            unsigned int hi23 = cvtpk_bf16(p[base + 6], p[base + 7]);
            u32x2 s1 = __builtin_amdgcn_permlane32_swap(lo01, hi01, false, false);  // {w0, w2}
            u32x2 s2 = __builtin_amdgcn_permlane32_swap(lo23, hi23, false, false);  // {w1, w3}
            u32x4 words = {s1[0], s2[0], s1[1], s2[1]};
            pa[c] = __builtin_bit_cast(bf16x8, words);
        }

        ctx0 = MFMA32(pa[0], vf00, ctx0);
        ctx0 = MFMA32(pa[1], vf10, ctx0);
        ctx1 = MFMA32(pa[0], vf01, ctx1);
        ctx1 = MFMA32(pa[1], vf11, ctx1);
    }

    float den_full = den + __shfl_xor(den, 32);

    if (kh == 1) {
        if (l < 32) lds_den[qg][l] = den_full;
#pragma unroll
        for (int r = 0; r < 16; ++r) {
            int qr = (r & 3) + 8 * (r >> 2) + 4 * h5;
            lds_ctx[qg][qr][lq] = ctx0[r];
            lds_ctx[qg][qr][32 + lq] = ctx1[r];
        }
    }
    __syncthreads();
    if (kh == 0) {
        float den_tot = den_full + lds_den[qg][lq];
#pragma unroll
        for (int r = 0; r < 16; ++r) {
            int qr = (r & 3) + 8 * (r >> 2) + 4 * h5;
            float dn = 1.0f / __shfl(den_tot, qr);
            size_t rowoff = ((size_t)b * SEQ + q0 + qr) * HID + hd * HDIM;
            out[rowoff + lq]      = (ctx0[r] + lds_ctx[qg][qr][lq]) * dn;
            out[rowoff + 32 + lq] = (ctx1[r] + lds_ctx[qg][qr][32 + lq]) * dn;
        }
    }
}

extern "C" void kernel_launch(void* const* d_in, const int* in_sizes, int n_in,
                              void* d_out, int out_size, void* d_ws, size_t ws_size,
                              hipStream_t stream) {
    const float* hs   = (const float*)d_in[0];
    const float* mask = (const float*)d_in[1];
    const float* Wq   = (const float*)d_in[2];
    const float* bq   = (const float*)d_in[3];
    const float* Wk   = (const float*)d_in[4];
    const float* bk   = (const float*)d_in[5];
    const float* Wv   = (const float*)d_in[6];
    const float* bv   = (const float*)d_in[7];
    float* out = (float*)d_out;

    char* ws = (char*)d_ws;
    unsigned short* hsb = (unsigned short*)(ws);
    unsigned short* wb  = (unsigned short*)(ws + 6291456);
    unsigned short* Qb  = (unsigned short*)(ws + 9830400);
    unsigned short* Kb  = (unsigned short*)(ws + 16121856);
    unsigned short* VTb = (unsigned short*)(ws + 22413312);

    cvt_all_kernel<<<4800, 256, 0, stream>>>((const float4*)hs, (const float4*)Wq,
                                             (const float4*)Wk, (const float4*)Wv,
                                             (ushort4*)hsb, (ushort4*)wb);
    qkv_gemm_kernel<<<576, 256, 0, stream>>>(hsb, wb, bq, bk, bv, Qb, Kb, VTb);
    attn_kernel<<<768, 256, 0, stream>>>(Qb, Kb, VTb, mask, out);
}